// Round 1
// baseline (895.557 us; speedup 1.0000x reference)
//
#include <hip/hip_runtime.h>
#include <stdint.h>

typedef unsigned short u16;
typedef __bf16 v8bf __attribute__((ext_vector_type(8)));
typedef float v4f __attribute__((ext_vector_type(4)));

__device__ __forceinline__ u16 f2bf(float f) {
  union { float f; unsigned u; } v; v.f = f;
  unsigned r = v.u + 0x7FFFu + ((v.u >> 16) & 1u);   // RNE
  return (u16)(r >> 16);
}
__device__ __forceinline__ float bf2f(u16 h) {
  union { unsigned u; float f; } v; v.u = ((unsigned)h) << 16;
  return v.f;
}

// ---------------- fp32 -> bf16 convert ----------------
__global__ void k_cvt(const float* __restrict__ s, u16* __restrict__ d, long n) {
  long i = ((long)blockIdx.x * blockDim.x + threadIdx.x) * 4;
  long stride = (long)gridDim.x * blockDim.x * 4;
  for (; i < n; i += stride) {
    float4 f = *(const float4*)(s + i);
    ushort4 o;
    o.x = f2bf(f.x); o.y = f2bf(f.y); o.z = f2bf(f.z); o.w = f2bf(f.w);
    *(ushort4*)(d + i) = o;
  }
}

// ---------------- avg-pool rows (window s) on a 256-col slice ----------------
// src: (4*2048, 1024) bf16, take cols [coloff, coloff+256); dst: (4*Ls, 256) bf16
__global__ void k_pool(const u16* __restrict__ src, u16* __restrict__ dst,
                       int s, int Ls, int coloff) {
  int idx = blockIdx.x * 256 + threadIdx.x;
  int c = idx & 255;
  int row = idx >> 8;           // b*Ls + t
  int b = row / Ls, t = row - b * Ls;
  const u16* p = src + (long)(b * 2048 + t * s) * 1024 + coloff + c;
  float acc = 0.f;
  for (int j = 0; j < s; j++) acc += bf2f(p[(long)j * 1024]);
  dst[idx] = f2bf(acc / (float)s);
}

// ---------------- block reduction helper (256 threads = 4 waves) ----------------
__device__ __forceinline__ float block_allreduce(float x, bool domax) {
  __shared__ float t[4];
  int lane = threadIdx.x & 63, w = threadIdx.x >> 6;
#pragma unroll
  for (int m = 32; m >= 1; m >>= 1) {
    float o = __shfl_xor(x, m, 64);
    x = domax ? fmaxf(x, o) : (x + o);
  }
  __syncthreads();              // protect t[] from previous use
  if (lane == 0) t[w] = x;
  __syncthreads();
  return domax ? fmaxf(fmaxf(t[0], t[1]), fmaxf(t[2], t[3]))
               : (t[0] + t[1] + t[2] + t[3]);
}

// ---------------- in-place row softmax over bf16 scores ----------------
template<int LK>
__global__ __launch_bounds__(256) void k_softmax(u16* __restrict__ P) {
  constexpr int E = LK / 256;
  long row = blockIdx.x;
  u16* p = P + row * (long)LK;
  int tid = threadIdx.x;
  float v[E];
  float mx = -1e30f;
#pragma unroll
  for (int i = 0; i < E; i++) { v[i] = bf2f(p[tid + i * 256]); mx = fmaxf(mx, v[i]); }
  mx = block_allreduce(mx, true);
  float s = 0.f;
#pragma unroll
  for (int i = 0; i < E; i++) { v[i] = __expf(v[i] - mx); s += v[i]; }
  s = block_allreduce(s, false);
  float inv = 1.0f / s;
#pragma unroll
  for (int i = 0; i < E; i++) p[tid + i * 256] = f2bf(v[i] * inv);
}

// scale-0 softmax: both heads of one (b,q) row; also writes fp32 head-mean to d_out
__global__ __launch_bounds__(256) void k_softmax0(u16* __restrict__ P, float* __restrict__ W0) {
  int bq = blockIdx.x;          // 0..8191
  int b = bq >> 11, q = bq & 2047;
  int tid = threadIdx.x;
  float pw[2][8];
  for (int h = 0; h < 2; h++) {
    u16* p = P + (((long)(b * 2 + h) * 2048 + q) * 2048);
    float v[8];
    float mx = -1e30f;
#pragma unroll
    for (int i = 0; i < 8; i++) { v[i] = bf2f(p[tid + i * 256]); mx = fmaxf(mx, v[i]); }
    mx = block_allreduce(mx, true);
    float s = 0.f;
#pragma unroll
    for (int i = 0; i < 8; i++) { v[i] = __expf(v[i] - mx); s += v[i]; }
    s = block_allreduce(s, false);
    float inv = 1.0f / s;
#pragma unroll
    for (int i = 0; i < 8; i++) { pw[h][i] = v[i] * inv; p[tid + i * 256] = f2bf(pw[h][i]); }
  }
  float* wrow = W0 + (long)bq * 2048;
#pragma unroll
  for (int i = 0; i < 8; i++) wrow[tid + i * 256] = 0.5f * (pw[0][i] + pw[1][i]);
}

// ---------------- generic batched bf16 MFMA GEMM: C = alpha*(A·B^T) + bias ----------------
// A: M x K row-major (ldA), B: N x K row-major (ldB). Two-level batch offsets:
// z = blockIdx.z; z1=z/nz2; z2=z%nz2; operand offset = z1*s?1 + z2*s?2.
// WBF: write bf16 else fp32. TR: write transposed into (b,h,hd,Ls) layout (Ls rows/batch).
template<int WBF, int TR>
__global__ __launch_bounds__(256) void k_gemm(
    const u16* __restrict__ A, long ldA, long sA1, long sA2,
    const u16* __restrict__ B, long ldB, long sB1, long sB2,
    void* __restrict__ Cv, long ldC, long sC1, long sC2,
    const float* __restrict__ bias, float alpha,
    int M, int N, int K, int nz2, int Ls)
{
  __shared__ u16 As[128][40];   // +8 pad: 80B row stride -> 2-way bank alias (free)
  __shared__ u16 Bs[128][40];
  int z = blockIdx.z;
  int z1 = z / nz2, z2 = z % nz2;
  A += (long)z1 * sA1 + (long)z2 * sA2;
  B += (long)z1 * sB1 + (long)z2 * sB2;
  long coff = (long)z1 * sC1 + (long)z2 * sC2;
  const int m0 = blockIdx.y * 128, n0 = blockIdx.x * 128;
  const int tid = threadIdx.x;
  const int lane = tid & 63;
  const int wave = tid >> 6;
  const int wr = (wave >> 1) * 64, wc = (wave & 1) * 64;
  const int q4 = lane >> 4, l16 = lane & 15;
  const int arow = tid >> 2;          // 0..63
  const int acol = (tid & 3) * 8;     // 0,8,16,24

  v4f acc[4][4];
#pragma unroll
  for (int i = 0; i < 4; i++)
#pragma unroll
    for (int j = 0; j < 4; j++) acc[i][j] = (v4f){0.f, 0.f, 0.f, 0.f};

  const u16* pA = A + (long)(m0 + arow) * ldA + acol;
  const u16* pB = B + (long)(n0 + arow) * ldB + acol;

  for (int kt = 0; kt < K; kt += 32) {
    uint4 a0 = *(const uint4*)(pA + kt);
    uint4 a1 = *(const uint4*)(pA + 64 * ldA + kt);
    uint4 b0 = *(const uint4*)(pB + kt);
    uint4 b1 = *(const uint4*)(pB + 64 * ldB + kt);
    *(uint4*)&As[arow][acol] = a0;
    *(uint4*)&As[arow + 64][acol] = a1;
    *(uint4*)&Bs[arow][acol] = b0;
    *(uint4*)&Bs[arow + 64][acol] = b1;
    __syncthreads();
    v8bf af[4], bf[4];
#pragma unroll
    for (int i = 0; i < 4; i++) af[i] = *(const v8bf*)&As[wr + i * 16 + l16][q4 * 8];
#pragma unroll
    for (int i = 0; i < 4; i++) bf[i] = *(const v8bf*)&Bs[wc + i * 16 + l16][q4 * 8];
#pragma unroll
    for (int mi = 0; mi < 4; mi++)
#pragma unroll
      for (int ni = 0; ni < 4; ni++)
        acc[mi][ni] = __builtin_amdgcn_mfma_f32_16x16x32_bf16(af[mi], bf[ni], acc[mi][ni], 0, 0, 0);
    __syncthreads();
  }

  // epilogue: D[row=quad*4+i][col=lane&15]  (verified layout)
#pragma unroll
  for (int mi = 0; mi < 4; mi++) {
    int rb = m0 + wr + mi * 16 + q4 * 4;
#pragma unroll
    for (int ni = 0; ni < 4; ni++) {
      int c = n0 + wc + ni * 16 + l16;
      float bv = bias ? bias[c] : 0.f;
#pragma unroll
      for (int i = 0; i < 4; i++) {
        int r = rb + i;
        float val = acc[mi][ni][i] * alpha + bv;
        if (TR) {
          int b = r / Ls, t = r - b * Ls;
          int h = c >> 7, n = c & 127;
          ((u16*)Cv)[coff + (((long)(b * 2 + h) * 128 + n) * Ls + t)] = f2bf(val);
        } else if (WBF) {
          ((u16*)Cv)[coff + (long)r * ldC + c] = f2bf(val);
        } else {
          ((float*)Cv)[coff + (long)r * ldC + c] = val;
        }
      }
    }
  }
}

static inline void launch_gemm(hipStream_t st, int mode,
    const u16* A, long ldA, long sA1, long sA2,
    const u16* B, long ldB, long sB1, long sB2,
    void* C, long ldC, long sC1, long sC2,
    const float* bias, float alpha,
    int M, int N, int K, int nz, int nz2, int Ls)
{
  dim3 g(N / 128, M / 128, nz), blk(256);
  if (mode == 0)
    k_gemm<0,0><<<g,blk,0,st>>>(A,ldA,sA1,sA2,B,ldB,sB1,sB2,C,ldC,sC1,sC2,bias,alpha,M,N,K,nz2,Ls);
  else if (mode == 1)
    k_gemm<1,0><<<g,blk,0,st>>>(A,ldA,sA1,sA2,B,ldB,sB1,sB2,C,ldC,sC1,sC2,bias,alpha,M,N,K,nz2,Ls);
  else
    k_gemm<1,1><<<g,blk,0,st>>>(A,ldA,sA1,sA2,B,ldB,sB1,sB2,C,ldC,sC1,sC2,bias,alpha,M,N,K,nz2,Ls);
}

extern "C" void kernel_launch(void* const* d_in, const int* in_sizes, int n_in,
                              void* d_out, int out_size, void* d_ws, size_t ws_size,
                              hipStream_t stream) {
  const float* query = (const float*)d_in[0];
  const float* key_  = (const float*)d_in[1];
  const float* value = (const float*)d_in[2];
  const float* wq    = (const float*)d_in[3];
  const float* bq    = (const float*)d_in[4];
  const float* wk    = (const float*)d_in[5];
  const float* bk    = (const float*)d_in[6];
  const float* wv    = (const float*)d_in[7];
  const float* bv    = (const float*)d_in[8];
  const float* in_w  = (const float*)d_in[9];
  const float* in_b  = (const float*)d_in[10];
  const float* out_w = (const float*)d_in[11];
  const float* out_b = (const float*)d_in[12];
  const float* fus_w = (const float*)d_in[13];
  const float* fus_b = (const float*)d_in[14];
  (void)in_sizes; (void)n_in; (void)out_size; (void)ws_size;

  float* outF  = (float*)d_out;                       // fused (4,2048,1024)
  float* outW0 = outF + (long)4 * 2048 * 1024;        // weights0 (4,2048,2048)

  // ---- workspace bump allocator (total ~240 MB) ----
  char* base = (char*)d_ws;
  size_t off = 0;
  auto alloc = [&](long elems) -> u16* {
    u16* p = (u16*)(base + off);
    off += (((size_t)elems * 2 + 255) & ~(size_t)255);
    return p;
  };
  const long NX = (long)8192 * 1024;
  u16* Xq    = alloc(NX);  u16* Xk  = alloc(NX);  u16* Xv = alloc(NX);
  u16* Wqb   = alloc(1024 * 1024); u16* Wkb = alloc(1024 * 1024);
  u16* Wvb   = alloc(1024 * 1024); u16* Wfb = alloc(1024 * 1024);
  u16* Winb  = alloc(4 * 768 * 256);
  u16* Woutb = alloc(4 * 256 * 256);
  u16* Qp    = alloc(NX);  u16* Kp  = alloc(NX);  u16* Vp = alloc(NX);
  u16* PoolK = alloc(7168L * 256);
  u16* PoolV = alloc(7168L * 256);
  u16* QH    = alloc((long)4 * 8192 * 256);
  u16* KH    = alloc(15360L * 256);
  u16* VHT   = alloc(15360L * 256);      // (b,h,hd,Ls) per scale
  u16* SC    = alloc((long)8 * 2048 * 2048);  // scores/probs, reused per scale
  u16* AO    = alloc((long)8192 * 256);       // attended pre-out-proj, reused
  u16* OUTS  = alloc((long)8192 * 1024);      // concat of per-scale outputs

  // ---- fp32 -> bf16 converts ----
  k_cvt<<<1024, 256, 0, stream>>>(query, Xq, NX);
  k_cvt<<<1024, 256, 0, stream>>>(key_,  Xk, NX);
  k_cvt<<<1024, 256, 0, stream>>>(value, Xv, NX);
  k_cvt<<<256, 256, 0, stream>>>(wq, Wqb, 1024 * 1024);
  k_cvt<<<256, 256, 0, stream>>>(wk, Wkb, 1024 * 1024);
  k_cvt<<<256, 256, 0, stream>>>(wv, Wvb, 1024 * 1024);
  k_cvt<<<256, 256, 0, stream>>>(fus_w, Wfb, 1024 * 1024);
  k_cvt<<<192, 256, 0, stream>>>(in_w, Winb, 4 * 768 * 256);
  k_cvt<<<64, 256, 0, stream>>>(out_w, Woutb, 4 * 256 * 256);

  // ---- q/k/v projections (8192 x 1024 x 1024) ----
  launch_gemm(stream, 1, Xq, 1024, 0, 0, Wqb, 1024, 0, 0, Qp, 1024, 0, 0,
              bq, 1.f, 8192, 1024, 1024, 1, 1, 0);
  launch_gemm(stream, 1, Xk, 1024, 0, 0, Wkb, 1024, 0, 0, Kp, 1024, 0, 0,
              bk, 1.f, 8192, 1024, 1024, 1, 1, 0);
  launch_gemm(stream, 1, Xv, 1024, 0, 0, Wvb, 1024, 0, 0, Vp, 1024, 0, 0,
              bv, 1.f, 8192, 1024, 1024, 1, 1, 0);

  const int poolOff[4] = {0, 0, 4096, 6144};   // rows before scale i (pooled buffers)
  const int khRow[4]   = {0, 8192, 12288, 14336}; // rows before scale i in KH/VHT

  // ---- pooling for s = 2,4,8 ----
  for (int i = 1; i < 4; i++) {
    int s = 1 << i, Ls = 2048 / s;
    k_pool<<<4 * Ls, 256, 0, stream>>>(Kp, PoolK + (long)poolOff[i] * 256, s, Ls, i * 256);
    k_pool<<<4 * Ls, 256, 0, stream>>>(Vp, PoolV + (long)poolOff[i] * 256, s, Ls, i * 256);
  }

  // ---- per-scale in-projections ----
  for (int i = 0; i < 4; i++) {
    int s = 1 << i, Ls = 2048 / s, rows = 4 * Ls;
    const u16* Wi = Winb + (long)i * 768 * 256;
    launch_gemm(stream, 1, Qp + i * 256, 1024, 0, 0, Wi, 256, 0, 0,
                QH + (long)i * 8192 * 256, 256, 0, 0, in_b + i * 768, 1.f,
                8192, 256, 256, 1, 1, 0);
    const u16* Ak = (i == 0) ? Kp : PoolK + (long)poolOff[i] * 256;
    const u16* Av = (i == 0) ? Vp : PoolV + (long)poolOff[i] * 256;
    long ldkv = (i == 0) ? 1024 : 256;
    launch_gemm(stream, 1, Ak, ldkv, 0, 0, Wi + 256 * 256, 256, 0, 0,
                KH + (long)khRow[i] * 256, 256, 0, 0, in_b + i * 768 + 256, 1.f,
                rows, 256, 256, 1, 1, 0);
    launch_gemm(stream, 2, Av, ldkv, 0, 0, Wi + 2 * 256 * 256, 256, 0, 0,
                VHT + (long)khRow[i] * 256, 0, 0, 0, in_b + i * 768 + 512, 1.f,
                rows, 256, 256, 1, 1, Ls);
  }

  // ---- per-scale attention + out-projection (SC/AO reused; stream-serialized) ----
  for (int i = 0; i < 4; i++) {
    int s = 1 << i, Lk = 2048 / s;
    // scores = qh . kh^T / sqrt(128), batched over z=(b,h) (8)
    launch_gemm(stream, 1,
                QH + (long)i * 8192 * 256, 256, (long)2048 * 256, 128,
                KH + (long)khRow[i] * 256, 256, (long)Lk * 256, 128,
                SC, Lk, (long)2 * 2048 * Lk, (long)2048 * Lk,
                nullptr, 0.08838834764831845f,
                2048, Lk, 128, 8, 2, 0);
    if (i == 0)      k_softmax0<<<8192, 256, 0, stream>>>(SC, outW0);
    else if (i == 1) k_softmax<1024><<<16384, 256, 0, stream>>>(SC);
    else if (i == 2) k_softmax<512><<<16384, 256, 0, stream>>>(SC);
    else             k_softmax<256><<<16384, 256, 0, stream>>>(SC);
    // out = probs . vh  (B operand = VHT rows, ld = Ls)
    launch_gemm(stream, 1,
                SC, Lk, (long)2 * 2048 * Lk, (long)2048 * Lk,
                VHT + (long)khRow[i] * 256, Lk, (long)2 * 128 * Lk, (long)128 * Lk,
                AO, 256, (long)2048 * 256, 128,
                nullptr, 1.f, 2048, 128, Lk, 8, 2, 0);
    // out-projection into concat buffer
    launch_gemm(stream, 1, AO, 256, 0, 0, Woutb + (long)i * 256 * 256, 256, 0, 0,
                OUTS + i * 256, 1024, 0, 0, out_b + i * 256, 1.f,
                8192, 256, 256, 1, 1, 0);
  }

  // ---- fusion GEMM: fp32 output straight to d_out ----
  launch_gemm(stream, 0, OUTS, 1024, 0, 0, Wfb, 1024, 0, 0,
              d_out, 1024, 0, 0, fus_b, 1.f, 8192, 1024, 1024, 1, 1, 0);
}

// Round 2
// 698.364 us; speedup vs baseline: 1.2824x; 1.2824x over previous
//
#include <hip/hip_runtime.h>
#include <stdint.h>

typedef unsigned short u16;
typedef __bf16 v8bf __attribute__((ext_vector_type(8)));
typedef float v4f __attribute__((ext_vector_type(4)));

__device__ __forceinline__ u16 f2bf(float f) {
  union { float f; unsigned u; } v; v.f = f;
  unsigned r = v.u + 0x7FFFu + ((v.u >> 16) & 1u);   // RNE
  return (u16)(r >> 16);
}
__device__ __forceinline__ float bf2f(u16 h) {
  union { unsigned u; float f; } v; v.u = ((unsigned)h) << 16;
  return v.f;
}
__device__ __forceinline__ long sel4(long4 v, int z) {
  return z == 0 ? v.x : z == 1 ? v.y : z == 2 ? v.z : v.w;
}
__device__ __forceinline__ int sel4i(int4 v, int z) {
  return z == 0 ? v.x : z == 1 ? v.y : z == 2 ? v.z : v.w;
}

// ---------------- fp32 -> bf16 convert ----------------
__global__ void k_cvt(const float* __restrict__ s, u16* __restrict__ d, long n) {
  long i = ((long)blockIdx.x * blockDim.x + threadIdx.x) * 4;
  long stride = (long)gridDim.x * blockDim.x * 4;
  for (; i < n; i += stride) {
    float4 f = *(const float4*)(s + i);
    ushort4 o;
    o.x = f2bf(f.x); o.y = f2bf(f.y); o.z = f2bf(f.z); o.w = f2bf(f.w);
    *(ushort4*)(d + i) = o;
  }
}

// ---------------- avg-pool rows (window s) on a 256-col slice ----------------
__global__ void k_pool(const u16* __restrict__ src, u16* __restrict__ dst,
                       int s, int Ls, int coloff) {
  int idx = blockIdx.x * 256 + threadIdx.x;
  int c = idx & 255;
  int row = idx >> 8;           // b*Ls + t
  int b = row / Ls, t = row - b * Ls;
  const u16* p = src + (long)(b * 2048 + t * s) * 1024 + coloff + c;
  float acc = 0.f;
  for (int j = 0; j < s; j++) acc += bf2f(p[(long)j * 1024]);
  dst[idx] = f2bf(acc / (float)s);
}

// ---------------- split-K reduce: AO = bf16(sum_ks PP[ks]) ----------------
template<int KS>
__global__ __launch_bounds__(256) void k_ksum(const float* __restrict__ P,
                                              u16* __restrict__ O, long n) {
  long i = ((long)blockIdx.x * 256 + threadIdx.x) * 4;
  if (i >= n) return;
  float4 s = *(const float4*)(P + i);
#pragma unroll
  for (int ks = 1; ks < KS; ks++) {
    float4 t = *(const float4*)(P + (long)ks * n + i);
    s.x += t.x; s.y += t.y; s.z += t.z; s.w += t.w;
  }
  ushort4 o;
  o.x = f2bf(s.x); o.y = f2bf(s.y); o.z = f2bf(s.z); o.w = f2bf(s.w);
  *(ushort4*)(O + i) = o;
}

// ---------------- block reduction helper (256 threads = 4 waves) ----------------
__device__ __forceinline__ float block_allreduce(float x, bool domax) {
  __shared__ float t[4];
  int lane = threadIdx.x & 63, w = threadIdx.x >> 6;
#pragma unroll
  for (int m = 32; m >= 1; m >>= 1) {
    float o = __shfl_xor(x, m, 64);
    x = domax ? fmaxf(x, o) : (x + o);
  }
  __syncthreads();
  if (lane == 0) t[w] = x;
  __syncthreads();
  return domax ? fmaxf(fmaxf(t[0], t[1]), fmaxf(t[2], t[3]))
               : (t[0] + t[1] + t[2] + t[3]);
}

// ---------------- in-place row softmax over bf16 scores ----------------
template<int LK>
__global__ __launch_bounds__(256) void k_softmax(u16* __restrict__ P) {
  constexpr int E = LK / 256;
  long row = blockIdx.x;
  u16* p = P + row * (long)LK;
  int tid = threadIdx.x;
  float v[E];
  float mx = -1e30f;
#pragma unroll
  for (int i = 0; i < E; i++) { v[i] = bf2f(p[tid + i * 256]); mx = fmaxf(mx, v[i]); }
  mx = block_allreduce(mx, true);
  float s = 0.f;
#pragma unroll
  for (int i = 0; i < E; i++) { v[i] = __expf(v[i] - mx); s += v[i]; }
  s = block_allreduce(s, false);
  float inv = 1.0f / s;
#pragma unroll
  for (int i = 0; i < E; i++) p[tid + i * 256] = f2bf(v[i] * inv);
}

// scale-0 softmax: both heads of one (b,q) row; also writes fp32 head-mean W0
__global__ __launch_bounds__(256) void k_softmax0(u16* __restrict__ P, float* __restrict__ W0) {
  int bq = blockIdx.x;          // 0..8191
  int b = bq >> 11, q = bq & 2047;
  int tid = threadIdx.x;
  float pw[2][8];
  for (int h = 0; h < 2; h++) {
    u16* p = P + (((long)(b * 2 + h) * 2048 + q) * 2048);
    float v[8];
    float mx = -1e30f;
#pragma unroll
    for (int i = 0; i < 8; i++) { v[i] = bf2f(p[tid + i * 256]); mx = fmaxf(mx, v[i]); }
    mx = block_allreduce(mx, true);
    float s = 0.f;
#pragma unroll
    for (int i = 0; i < 8; i++) { v[i] = __expf(v[i] - mx); s += v[i]; }
    s = block_allreduce(s, false);
    float inv = 1.0f / s;
#pragma unroll
    for (int i = 0; i < 8; i++) { pw[h][i] = v[i] * inv; p[tid + i * 256] = f2bf(pw[h][i]); }
  }
  float* wrow = W0 + (long)bq * 2048;
#pragma unroll
  for (int i = 0; i < 8; i++) wrow[tid + i * 256] = 0.5f * (pw[0][i] + pw[1][i]);
}

// ---------------- 128-tile batched bf16 MFMA GEMM with split-K ----------------
// C = alpha*(A . B^T) + bias.  z = ((z1*nz2)+z2)*KS + ks
// A: M x K row-major slice starting at ks*K; WBF: bf16 out else fp32.
template<int WBF>
__global__ __launch_bounds__(256) void k_gemm(
    const u16* __restrict__ A, long ldA, long sA1, long sA2,
    const u16* __restrict__ B, long ldB, long sB1, long sB2,
    void* __restrict__ Cv, long ldC, long sC1, long sC2, long sCk,
    const float* __restrict__ bias, long sBias, float alpha,
    int M, int N, int K, int nz2, int KS)
{
  __shared__ u16 As[128][40];   // +8 pad
  __shared__ u16 Bs[128][40];
  int z = blockIdx.z;
  int ks = z % KS; int zz = z / KS;
  int z1 = zz / nz2, z2 = zz - z1 * nz2;
  A += (long)z1 * sA1 + (long)z2 * sA2 + (long)ks * K;
  B += (long)z1 * sB1 + (long)z2 * sB2 + (long)ks * K;
  long coff = (long)z1 * sC1 + (long)z2 * sC2 + (long)ks * sCk;
  const float* bz = bias ? bias + (long)z2 * sBias : nullptr;
  const int m0 = blockIdx.y * 128, n0 = blockIdx.x * 128;
  const int tid = threadIdx.x;
  const int lane = tid & 63;
  const int wave = tid >> 6;
  const int wr = (wave >> 1) * 64, wc = (wave & 1) * 64;
  const int q4 = lane >> 4, l16 = lane & 15;
  const int arow = tid >> 2;
  const int acol = (tid & 3) * 8;

  v4f acc[4][4];
#pragma unroll
  for (int i = 0; i < 4; i++)
#pragma unroll
    for (int j = 0; j < 4; j++) acc[i][j] = (v4f){0.f, 0.f, 0.f, 0.f};

  const u16* pA = A + (long)(m0 + arow) * ldA + acol;
  const u16* pB = B + (long)(n0 + arow) * ldB + acol;

  for (int kt = 0; kt < K; kt += 32) {
    uint4 a0 = *(const uint4*)(pA + kt);
    uint4 a1 = *(const uint4*)(pA + 64 * ldA + kt);
    uint4 b0 = *(const uint4*)(pB + kt);
    uint4 b1 = *(const uint4*)(pB + 64 * ldB + kt);
    *(uint4*)&As[arow][acol] = a0;
    *(uint4*)&As[arow + 64][acol] = a1;
    *(uint4*)&Bs[arow][acol] = b0;
    *(uint4*)&Bs[arow + 64][acol] = b1;
    __syncthreads();
    v8bf af[4], bf[4];
#pragma unroll
    for (int i = 0; i < 4; i++) af[i] = *(const v8bf*)&As[wr + i * 16 + l16][q4 * 8];
#pragma unroll
    for (int i = 0; i < 4; i++) bf[i] = *(const v8bf*)&Bs[wc + i * 16 + l16][q4 * 8];
#pragma unroll
    for (int mi = 0; mi < 4; mi++)
#pragma unroll
      for (int ni = 0; ni < 4; ni++)
        acc[mi][ni] = __builtin_amdgcn_mfma_f32_16x16x32_bf16(af[mi], bf[ni], acc[mi][ni], 0, 0, 0);
    __syncthreads();
  }

#pragma unroll
  for (int mi = 0; mi < 4; mi++) {
    int rb = m0 + wr + mi * 16 + q4 * 4;
#pragma unroll
    for (int ni = 0; ni < 4; ni++) {
      int c = n0 + wc + ni * 16 + l16;
      float bv = bz ? bz[c] : 0.f;
#pragma unroll
      for (int i = 0; i < 4; i++) {
        int r = rb + i;
        float val = acc[mi][ni][i] * alpha + bv;
        if (WBF) ((u16*)Cv)[coff + (long)r * ldC + c] = f2bf(val);
        else     ((float*)Cv)[coff + (long)r * ldC + c] = val;
      }
    }
  }
}

// ---------------- 64x64-tile batched GEMM for small-N ops (N=256) ----------------
// Per-z: A offset (aOff), C offset (cOff), rows (Mz). B/bias linear strides.
// TR=1: write transposed into (b,h,hd,Ls) with per-z Ls (power of 2).
template<int TR>
__global__ __launch_bounds__(256) void k_gemm_sm(
    const u16* __restrict__ A, long ldA, long4 aOff,
    const u16* __restrict__ B, long ldB, long sB,
    u16* __restrict__ C, long ldC, long4 cOff,
    const float* __restrict__ bias, long sBias,
    int4 Mz, int K, int4 Lsz)
{
  int z = blockIdx.z;
  int M = sel4i(Mz, z);
  int m0 = blockIdx.y * 64;
  if (m0 >= M) return;
  int n0 = blockIdx.x * 64;
  A += sel4(aOff, z);
  B += (long)z * sB;
  long coff = sel4(cOff, z);
  const float* bz = bias + (long)z * sBias;
  int Ls = sel4i(Lsz, z);
  int lsh = 31 - __clz(Ls);

  __shared__ u16 As[64][40];
  __shared__ u16 Bs[64][40];
  const int tid = threadIdx.x;
  const int lane = tid & 63, wave = tid >> 6;
  const int wr = (wave >> 1) * 32, wc = (wave & 1) * 32;
  const int q4 = lane >> 4, l16 = lane & 15;
  const int arow = tid >> 2, acol = (tid & 3) * 8;

  v4f acc[2][2];
#pragma unroll
  for (int i = 0; i < 2; i++)
#pragma unroll
    for (int j = 0; j < 2; j++) acc[i][j] = (v4f){0.f, 0.f, 0.f, 0.f};

  const u16* pA = A + (long)(m0 + arow) * ldA + acol;
  const u16* pB = B + (long)(n0 + arow) * ldB + acol;

  for (int kt = 0; kt < K; kt += 32) {
    uint4 a0 = *(const uint4*)(pA + kt);
    uint4 b0 = *(const uint4*)(pB + kt);
    *(uint4*)&As[arow][acol] = a0;
    *(uint4*)&Bs[arow][acol] = b0;
    __syncthreads();
    v8bf af[2], bf[2];
#pragma unroll
    for (int i = 0; i < 2; i++) af[i] = *(const v8bf*)&As[wr + i * 16 + l16][q4 * 8];
#pragma unroll
    for (int i = 0; i < 2; i++) bf[i] = *(const v8bf*)&Bs[wc + i * 16 + l16][q4 * 8];
#pragma unroll
    for (int mi = 0; mi < 2; mi++)
#pragma unroll
      for (int ni = 0; ni < 2; ni++)
        acc[mi][ni] = __builtin_amdgcn_mfma_f32_16x16x32_bf16(af[mi], bf[ni], acc[mi][ni], 0, 0, 0);
    __syncthreads();
  }

#pragma unroll
  for (int mi = 0; mi < 2; mi++) {
    int rb = m0 + wr + mi * 16 + q4 * 4;
#pragma unroll
    for (int ni = 0; ni < 2; ni++) {
      int c = n0 + wc + ni * 16 + l16;
      float bv = bz[c];
#pragma unroll
      for (int i = 0; i < 4; i++) {
        int r = rb + i;
        float val = acc[mi][ni][i] + bv;
        if (TR) {
          int b = r >> lsh, t = r & (Ls - 1);
          int h = c >> 7, n = c & 127;
          C[coff + (((long)(b * 2 + h) * 128 + n) << lsh) + t] = f2bf(val);
        } else {
          C[coff + (long)r * ldC + c] = f2bf(val);
        }
      }
    }
  }
}

extern "C" void kernel_launch(void* const* d_in, const int* in_sizes, int n_in,
                              void* d_out, int out_size, void* d_ws, size_t ws_size,
                              hipStream_t stream) {
  const float* query = (const float*)d_in[0];
  const float* key_  = (const float*)d_in[1];
  const float* value = (const float*)d_in[2];
  const float* wq    = (const float*)d_in[3];
  const float* bq    = (const float*)d_in[4];
  const float* wk    = (const float*)d_in[5];
  const float* bk    = (const float*)d_in[6];
  const float* wv    = (const float*)d_in[7];
  const float* bv    = (const float*)d_in[8];
  const float* in_w  = (const float*)d_in[9];
  const float* in_b  = (const float*)d_in[10];
  const float* out_w = (const float*)d_in[11];
  const float* out_b = (const float*)d_in[12];
  const float* fus_w = (const float*)d_in[13];
  const float* fus_b = (const float*)d_in[14];
  (void)in_sizes; (void)n_in; (void)out_size; (void)ws_size;

  float* outF  = (float*)d_out;
  float* outW0 = outF + (long)4 * 2048 * 1024;

  // ---- workspace layout (~200 MB, with region aliasing) ----
  char* base = (char*)d_ws;
  size_t off = 0;
  auto alloc = [&](size_t bytes) -> void* {
    void* p = base + off;
    off = (off + bytes + 255) & ~(size_t)255;
    return p;
  };
  const long NX = (long)8192 * 1024;
  u16* Wqb   = (u16*)alloc(1024 * 1024 * 2);   // Wqb,Wkb,Wvb contiguous (stride 1M el)
  u16* Wkb   = (u16*)alloc(1024 * 1024 * 2);
  u16* Wvb   = (u16*)alloc(1024 * 1024 * 2);
  u16* Wfb   = (u16*)alloc(1024 * 1024 * 2);
  u16* Winb  = (u16*)alloc(4 * 768 * 256 * 2);
  u16* Woutb = (u16*)alloc(4 * 256 * 256 * 2);
  float* Bias3 = (float*)alloc(3 * 1024 * 4);
  // region X: converted inputs (48 MB); after QKV proj reused for QH/KH/VHT
  char* regX = (char*)alloc((size_t)3 * NX * 2);
  u16* Xq = (u16*)regX; u16* Xk = Xq + NX; u16* Xv = Xk + NX;
  u16* QH  = (u16*)regX;                        // 4*8192*256 el = 16 MB
  u16* KH  = QH + (long)4 * 8192 * 256;         // 15360*256 el
  u16* VHT = KH + (long)15360 * 256;            // 15360*256 el  (total 32.5 MB <= 48)
  // region Y: Qp/Kp/Vp (48 MB); after in-proj reused for PP (32 MB) + AO (16 MB)
  char* regY = (char*)alloc((size_t)3 * NX * 2);
  u16* Qp = (u16*)regY; u16* Kp = Qp + NX; u16* Vp = Kp + NX;
  float* PP = (float*)regY;                     // up to 4 * 2M fp32 = 32 MB
  u16* AO   = (u16*)(regY + (size_t)32 * 1024 * 1024);  // 4 * 2M bf16 = 16 MB
  u16* PoolK = (u16*)alloc((size_t)15360 * 256 * 2);
  u16* PoolV = (u16*)alloc((size_t)15360 * 256 * 2);
  u16* SC    = (u16*)alloc((size_t)8 * 2048 * 2048 * 2);
  u16* OUTS  = (u16*)alloc((size_t)8192 * 1024 * 2);

  const long rOff[4] = {0, 8192, 12288, 14336};      // row offsets in PoolK/KH/VHT
  const long AOsz = (long)8192 * 256;                // 2M elements per scale

  // ---- converts ----
  k_cvt<<<1024, 256, 0, stream>>>(query, Xq, NX);
  k_cvt<<<1024, 256, 0, stream>>>(key_,  Xk, NX);
  k_cvt<<<1024, 256, 0, stream>>>(value, Xv, NX);
  k_cvt<<<256, 256, 0, stream>>>(wq, Wqb, 1024 * 1024);
  k_cvt<<<256, 256, 0, stream>>>(wk, Wkb, 1024 * 1024);
  k_cvt<<<256, 256, 0, stream>>>(wv, Wvb, 1024 * 1024);
  k_cvt<<<256, 256, 0, stream>>>(fus_w, Wfb, 1024 * 1024);
  k_cvt<<<192, 256, 0, stream>>>(in_w, Winb, 4 * 768 * 256);
  k_cvt<<<64, 256, 0, stream>>>(out_w, Woutb, 4 * 256 * 256);
  hipMemcpyAsync(Bias3,        bq, 4096, hipMemcpyDeviceToDevice, stream);
  hipMemcpyAsync(Bias3 + 1024, bk, 4096, hipMemcpyDeviceToDevice, stream);
  hipMemcpyAsync(Bias3 + 2048, bv, 4096, hipMemcpyDeviceToDevice, stream);

  // ---- QKV projections, batched z=3: grid (8,64,3) ----
  k_gemm<1><<<dim3(8, 64, 3), 256, 0, stream>>>(
      Xq, 1024, 0, NX, Wqb, 1024, 0, (long)1024 * 1024,
      Qp, 1024, 0, NX, 0, Bias3, 1024, 1.f, 8192, 1024, 1024, 3, 1);

  // ---- pooling (s=1 copy for scale 0 unifies layout) ----
  for (int i = 0; i < 4; i++) {
    int s = 1 << i, Ls = 2048 >> i;
    k_pool<<<4 * Ls, 256, 0, stream>>>(Kp, PoolK + rOff[i] * 256, s, Ls, i * 256);
    k_pool<<<4 * Ls, 256, 0, stream>>>(Vp, PoolV + rOff[i] * 256, s, Ls, i * 256);
  }

  // ---- in-projections, each batched over 4 scales: grid (4,128,4) ----
  {
    long4 aQ = {0, 256, 512, 768};
    long4 cQ = {0, AOsz, 2 * AOsz, 3 * AOsz};
    int4  m8 = {8192, 8192, 8192, 8192};
    long4 aP = {rOff[0] * 256, rOff[1] * 256, rOff[2] * 256, rOff[3] * 256};
    int4  mP = {8192, 4096, 2048, 1024};
    int4  ls = {2048, 1024, 512, 256};
    k_gemm_sm<0><<<dim3(4, 128, 4), 256, 0, stream>>>(
        Qp, 1024, aQ, Winb, 256, (long)768 * 256,
        QH, 256, cQ, in_b, 768, m8, 256, ls);
    k_gemm_sm<0><<<dim3(4, 128, 4), 256, 0, stream>>>(
        PoolK, 256, aP, Winb + 256 * 256, 256, (long)768 * 256,
        KH, 256, aP, in_b + 256, 768, mP, 256, ls);
    k_gemm_sm<1><<<dim3(4, 128, 4), 256, 0, stream>>>(
        PoolV, 256, aP, Winb + 2 * 256 * 256, 256, (long)768 * 256,
        VHT, 0, aP, in_b + 512, 768, mP, 256, ls);
  }

  // ---- per-scale attention ----
  const int ksArr[4] = {4, 4, 2, 2};
  for (int i = 0; i < 4; i++) {
    int Lk = 2048 >> i;
    // scores = qh . kh^T / sqrt(128): grid (Lk/128, 16, 8)
    k_gemm<1><<<dim3(Lk / 128, 16, 8), 256, 0, stream>>>(
        QH + (long)i * AOsz, 256, (long)2048 * 256, 128,
        KH + rOff[i] * 256, 256, (long)Lk * 256, 128,
        SC, Lk, (long)2 * 2048 * Lk, (long)2048 * Lk, 0,
        nullptr, 0, 0.08838834764831845f, 2048, Lk, 128, 2, 1);
    if (i == 0)      k_softmax0<<<8192, 256, 0, stream>>>(SC, outW0);
    else if (i == 1) k_softmax<1024><<<16384, 256, 0, stream>>>(SC);
    else if (i == 2) k_softmax<512><<<16384, 256, 0, stream>>>(SC);
    else             k_softmax<256><<<16384, 256, 0, stream>>>(SC);
    // PV with split-K: fp32 partials, grid (1, 16, 8*KS)
    int KS = ksArr[i], Kper = Lk / KS;
    k_gemm<0><<<dim3(1, 16, 8 * KS), 256, 0, stream>>>(
        SC, Lk, (long)2 * 2048 * Lk, (long)2048 * Lk,
        VHT + rOff[i] * 256, Lk, (long)2 * 128 * Lk, (long)128 * Lk,
        PP, 256, (long)2048 * 256, 128, AOsz,
        nullptr, 0, 1.f, 2048, 128, Kper, 2, KS);
    if (KS == 4) k_ksum<4><<<2048, 256, 0, stream>>>(PP, AO + (long)i * AOsz, AOsz);
    else         k_ksum<2><<<2048, 256, 0, stream>>>(PP, AO + (long)i * AOsz, AOsz);
  }

  // ---- out-projections batched z=4: grid (4,128,4) ----
  {
    long4 aA = {0, AOsz, 2 * AOsz, 3 * AOsz};
    long4 cO = {0, 256, 512, 768};
    int4  m8 = {8192, 8192, 8192, 8192};
    int4  ls = {1, 1, 1, 1};
    k_gemm_sm<0><<<dim3(4, 128, 4), 256, 0, stream>>>(
        AO, 256, aA, Woutb, 256, (long)256 * 256,
        OUTS, 1024, cO, out_b, 256, m8, 256, ls);
  }

  // ---- fusion GEMM: fp32 out ----
  k_gemm<0><<<dim3(8, 64, 1), 256, 0, stream>>>(
      OUTS, 1024, 0, 0, Wfb, 1024, 0, 0,
      d_out, 1024, 0, 0, 0, fus_b, 1024, 1.f, 8192, 1024, 1024, 1, 1);
}

// Round 3
// 693.449 us; speedup vs baseline: 1.2915x; 1.0071x over previous
//
#include <hip/hip_runtime.h>
#include <stdint.h>

typedef unsigned short u16;
typedef __bf16 v8bf __attribute__((ext_vector_type(8)));
typedef float v4f __attribute__((ext_vector_type(4)));
typedef __attribute__((address_space(3))) unsigned lds_t;
typedef const __attribute__((address_space(1))) unsigned g_t;

__device__ __forceinline__ u16 f2bf(float f) {
  union { float f; unsigned u; } v; v.f = f;
  unsigned r = v.u + 0x7FFFu + ((v.u >> 16) & 1u);   // RNE
  return (u16)(r >> 16);
}
__device__ __forceinline__ float bf2f(u16 h) {
  union { unsigned u; float f; } v; v.u = ((unsigned)h) << 16;
  return v.f;
}
__device__ __forceinline__ long sel4(long4 v, int z) {
  return z == 0 ? v.x : z == 1 ? v.y : z == 2 ? v.z : v.w;
}
__device__ __forceinline__ int sel4i(int4 v, int z) {
  return z == 0 ? v.x : z == 1 ? v.y : z == 2 ? v.z : v.w;
}

// ---------------- fp32 -> bf16 convert ----------------
__global__ void k_cvt(const float* __restrict__ s, u16* __restrict__ d, long n) {
  long i = ((long)blockIdx.x * blockDim.x + threadIdx.x) * 4;
  long stride = (long)gridDim.x * blockDim.x * 4;
  for (; i < n; i += stride) {
    float4 f = *(const float4*)(s + i);
    ushort4 o;
    o.x = f2bf(f.x); o.y = f2bf(f.y); o.z = f2bf(f.z); o.w = f2bf(f.w);
    *(ushort4*)(d + i) = o;
  }
}

// ---------------- avg-pool rows (window s) on a 256-col slice ----------------
__global__ void k_pool(const u16* __restrict__ src, u16* __restrict__ dst,
                       int s, int Ls, int coloff) {
  int idx = blockIdx.x * 256 + threadIdx.x;
  int c = idx & 255;
  int row = idx >> 8;           // b*Ls + t
  int b = row / Ls, t = row - b * Ls;
  const u16* p = src + (long)(b * 2048 + t * s) * 1024 + coloff + c;
  float acc = 0.f;
  for (int j = 0; j < s; j++) acc += bf2f(p[(long)j * 1024]);
  dst[idx] = f2bf(acc / (float)s);
}

// ---------------- split-K reduce: AO = bf16(sum_ks PP[ks]) ----------------
template<int KS>
__global__ __launch_bounds__(256) void k_ksum(const float* __restrict__ P,
                                              u16* __restrict__ O, long n) {
  long i = ((long)blockIdx.x * 256 + threadIdx.x) * 4;
  if (i >= n) return;
  float4 s = *(const float4*)(P + i);
#pragma unroll
  for (int ks = 1; ks < KS; ks++) {
    float4 t = *(const float4*)(P + (long)ks * n + i);
    s.x += t.x; s.y += t.y; s.z += t.z; s.w += t.w;
  }
  ushort4 o;
  o.x = f2bf(s.x); o.y = f2bf(s.y); o.z = f2bf(s.z); o.w = f2bf(s.w);
  *(ushort4*)(O + i) = o;
}

// ---------------- block reduction helper (256 threads = 4 waves) ----------------
__device__ __forceinline__ float block_allreduce(float x, bool domax) {
  __shared__ float t[4];
  int lane = threadIdx.x & 63, w = threadIdx.x >> 6;
#pragma unroll
  for (int m = 32; m >= 1; m >>= 1) {
    float o = __shfl_xor(x, m, 64);
    x = domax ? fmaxf(x, o) : (x + o);
  }
  __syncthreads();
  if (lane == 0) t[w] = x;
  __syncthreads();
  return domax ? fmaxf(fmaxf(t[0], t[1]), fmaxf(t[2], t[3]))
               : (t[0] + t[1] + t[2] + t[3]);
}

// ---------------- in-place row softmax over bf16 scores ----------------
template<int LK>
__global__ __launch_bounds__(256) void k_softmax(u16* __restrict__ P) {
  constexpr int E = LK / 256;
  long row = blockIdx.x;
  u16* p = P + row * (long)LK;
  int tid = threadIdx.x;
  float v[E];
  float mx = -1e30f;
#pragma unroll
  for (int i = 0; i < E; i++) { v[i] = bf2f(p[tid + i * 256]); mx = fmaxf(mx, v[i]); }
  mx = block_allreduce(mx, true);
  float s = 0.f;
#pragma unroll
  for (int i = 0; i < E; i++) { v[i] = __expf(v[i] - mx); s += v[i]; }
  s = block_allreduce(s, false);
  float inv = 1.0f / s;
#pragma unroll
  for (int i = 0; i < E; i++) p[tid + i * 256] = f2bf(v[i] * inv);
}

// scale-0 softmax: both heads of one (b,q) row; also writes fp32 head-mean W0
__global__ __launch_bounds__(256) void k_softmax0(u16* __restrict__ P, float* __restrict__ W0) {
  int bq = blockIdx.x;          // 0..8191
  int b = bq >> 11, q = bq & 2047;
  int tid = threadIdx.x;
  float pw[2][8];
  for (int h = 0; h < 2; h++) {
    u16* p = P + (((long)(b * 2 + h) * 2048 + q) * 2048);
    float v[8];
    float mx = -1e30f;
#pragma unroll
    for (int i = 0; i < 8; i++) { v[i] = bf2f(p[tid + i * 256]); mx = fmaxf(mx, v[i]); }
    mx = block_allreduce(mx, true);
    float s = 0.f;
#pragma unroll
    for (int i = 0; i < 8; i++) { v[i] = __expf(v[i] - mx); s += v[i]; }
    s = block_allreduce(s, false);
    float inv = 1.0f / s;
#pragma unroll
    for (int i = 0; i < 8; i++) { pw[h][i] = v[i] * inv; p[tid + i * 256] = f2bf(pw[h][i]); }
  }
  float* wrow = W0 + (long)bq * 2048;
#pragma unroll
  for (int i = 0; i < 8; i++) wrow[tid + i * 256] = 0.5f * (pw[0][i] + pw[1][i]);
}

// ---------------- 128x128-tile batched bf16 MFMA GEMM, global_load_lds staging ----
// C = alpha*(A . B^T) + bias.  z = ((z1*nz2)+z2)*KS + ks (split-K).
// Unpadded LDS [128][32]: required by global_load_lds (wave-uniform base + lane*16B).
template<int WBF>
__global__ __launch_bounds__(256) void k_gemm(
    const u16* __restrict__ A, long ldA, long sA1, long sA2,
    const u16* __restrict__ B, long ldB, long sB1, long sB2,
    void* __restrict__ Cv, long ldC, long sC1, long sC2, long sCk,
    const float* __restrict__ bias, long sBias, float alpha,
    int M, int N, int K, int nz2, int KS)
{
  __shared__ u16 As[128][32];
  __shared__ u16 Bs[128][32];
  int z = blockIdx.z;
  int ks = z % KS; int zz = z / KS;
  int z1 = zz / nz2, z2 = zz - z1 * nz2;
  A += (long)z1 * sA1 + (long)z2 * sA2 + (long)ks * K;
  B += (long)z1 * sB1 + (long)z2 * sB2 + (long)ks * K;
  long coff = (long)z1 * sC1 + (long)z2 * sC2 + (long)ks * sCk;
  const float* bz = bias ? bias + (long)z2 * sBias : nullptr;
  const int m0 = blockIdx.y * 128, n0 = blockIdx.x * 128;
  const int tid = threadIdx.x;
  const int lane = tid & 63;
  const int wave = tid >> 6;
  const int wr = (wave >> 1) * 64, wc = (wave & 1) * 64;
  const int q4 = lane >> 4, l16 = lane & 15;

  // staging: each wave covers 16 rows per issue (lane -> row = lane>>2, 16B chunk = lane&3)
  const int srow = wave * 16 + (lane >> 2);
  const int scol = (lane & 3) * 8;
  const u16* gA = A + (long)(m0 + srow) * ldA + scol;
  const u16* gB = B + (long)(n0 + srow) * ldB + scol;
  lds_t* lA0 = (lds_t*)&As[wave * 16][0];
  lds_t* lA1 = (lds_t*)&As[64 + wave * 16][0];
  lds_t* lB0 = (lds_t*)&Bs[wave * 16][0];
  lds_t* lB1 = (lds_t*)&Bs[64 + wave * 16][0];

  v4f acc[4][4];
#pragma unroll
  for (int i = 0; i < 4; i++)
#pragma unroll
    for (int j = 0; j < 4; j++) acc[i][j] = (v4f){0.f, 0.f, 0.f, 0.f};

  for (int kt = 0; kt < K; kt += 32) {
    __builtin_amdgcn_global_load_lds((g_t*)(gA + kt), (lds_t*)lA0, 16, 0, 0);
    __builtin_amdgcn_global_load_lds((g_t*)(gA + 64 * ldA + kt), (lds_t*)lA1, 16, 0, 0);
    __builtin_amdgcn_global_load_lds((g_t*)(gB + kt), (lds_t*)lB0, 16, 0, 0);
    __builtin_amdgcn_global_load_lds((g_t*)(gB + 64 * ldB + kt), (lds_t*)lB1, 16, 0, 0);
    __syncthreads();
    v8bf af[4], bf[4];
#pragma unroll
    for (int i = 0; i < 4; i++) af[i] = *(const v8bf*)&As[wr + i * 16 + l16][q4 * 8];
#pragma unroll
    for (int i = 0; i < 4; i++) bf[i] = *(const v8bf*)&Bs[wc + i * 16 + l16][q4 * 8];
#pragma unroll
    for (int mi = 0; mi < 4; mi++)
#pragma unroll
      for (int ni = 0; ni < 4; ni++)
        acc[mi][ni] = __builtin_amdgcn_mfma_f32_16x16x32_bf16(af[mi], bf[ni], acc[mi][ni], 0, 0, 0);
    __syncthreads();
  }

#pragma unroll
  for (int mi = 0; mi < 4; mi++) {
    int rb = m0 + wr + mi * 16 + q4 * 4;
#pragma unroll
    for (int ni = 0; ni < 4; ni++) {
      int c = n0 + wc + ni * 16 + l16;
      float bv = bz ? bz[c] : 0.f;
#pragma unroll
      for (int i = 0; i < 4; i++) {
        int r = rb + i;
        float val = acc[mi][ni][i] * alpha + bv;
        if (WBF) ((u16*)Cv)[coff + (long)r * ldC + c] = f2bf(val);
        else     ((float*)Cv)[coff + (long)r * ldC + c] = val;
      }
    }
  }
}

// ---------------- 128x64-tile batched GEMM for small-N ops (N=256) ----------------
// Per-z: A offset (aOff), C offset (cOff), rows (Mz). B/bias linear strides.
// TR=1: write transposed into (b,h,hd,Ls) with per-z Ls (power of 2).
template<int TR>
__global__ __launch_bounds__(256) void k_gemm_sm(
    const u16* __restrict__ A, long ldA, long4 aOff,
    const u16* __restrict__ B, long ldB, long sB,
    u16* __restrict__ C, long ldC, long4 cOff,
    const float* __restrict__ bias, long sBias,
    int4 Mz, int K, int4 Lsz)
{
  int z = blockIdx.z;
  int M = sel4i(Mz, z);
  int m0 = blockIdx.y * 128;
  if (m0 >= M) return;
  int n0 = blockIdx.x * 64;
  const u16* Az = A + sel4(aOff, z);
  const u16* Bz = B + (long)z * sB;
  long coff = sel4(cOff, z);
  const float* bz = bias + (long)z * sBias;
  int Ls = sel4i(Lsz, z);
  int lsh = 31 - __clz(Ls);

  __shared__ u16 As[128][32];
  __shared__ u16 Bs[64][32];
  const int tid = threadIdx.x;
  const int lane = tid & 63, wave = tid >> 6;
  const int q4 = lane >> 4, l16 = lane & 15;
  const int srow = wave * 16 + (lane >> 2);
  const int scol = (lane & 3) * 8;
  const u16* gA = Az + (long)(m0 + srow) * ldA + scol;
  const u16* gB = Bz + (long)(n0 + srow) * ldB + scol;
  lds_t* lA0 = (lds_t*)&As[wave * 16][0];
  lds_t* lA1 = (lds_t*)&As[64 + wave * 16][0];
  lds_t* lB0 = (lds_t*)&Bs[wave * 16][0];

  v4f acc[2][4];
#pragma unroll
  for (int i = 0; i < 2; i++)
#pragma unroll
    for (int j = 0; j < 4; j++) acc[i][j] = (v4f){0.f, 0.f, 0.f, 0.f};

  for (int kt = 0; kt < K; kt += 32) {
    __builtin_amdgcn_global_load_lds((g_t*)(gA + kt), (lds_t*)lA0, 16, 0, 0);
    __builtin_amdgcn_global_load_lds((g_t*)(gA + 64 * ldA + kt), (lds_t*)lA1, 16, 0, 0);
    __builtin_amdgcn_global_load_lds((g_t*)(gB + kt), (lds_t*)lB0, 16, 0, 0);
    __syncthreads();
    v8bf af[2], bf[4];
#pragma unroll
    for (int i = 0; i < 2; i++) af[i] = *(const v8bf*)&As[wave * 32 + i * 16 + l16][q4 * 8];
#pragma unroll
    for (int j = 0; j < 4; j++) bf[j] = *(const v8bf*)&Bs[j * 16 + l16][q4 * 8];
#pragma unroll
    for (int mi = 0; mi < 2; mi++)
#pragma unroll
      for (int ni = 0; ni < 4; ni++)
        acc[mi][ni] = __builtin_amdgcn_mfma_f32_16x16x32_bf16(af[mi], bf[ni], acc[mi][ni], 0, 0, 0);
    __syncthreads();
  }

#pragma unroll
  for (int mi = 0; mi < 2; mi++) {
    int rb = m0 + wave * 32 + mi * 16 + q4 * 4;
#pragma unroll
    for (int ni = 0; ni < 4; ni++) {
      int c = n0 + ni * 16 + l16;
      float bv = bz[c];
#pragma unroll
      for (int i = 0; i < 4; i++) {
        int r = rb + i;
        float val = acc[mi][ni][i] + bv;
        if (TR) {
          int b = r >> lsh, t = r & (Ls - 1);
          int h = c >> 7, n = c & 127;
          C[coff + (((long)(b * 2 + h) * 128 + n) << lsh) + t] = f2bf(val);
        } else {
          C[coff + (long)r * ldC + c] = f2bf(val);
        }
      }
    }
  }
}

extern "C" void kernel_launch(void* const* d_in, const int* in_sizes, int n_in,
                              void* d_out, int out_size, void* d_ws, size_t ws_size,
                              hipStream_t stream) {
  const float* query = (const float*)d_in[0];
  const float* key_  = (const float*)d_in[1];
  const float* value = (const float*)d_in[2];
  const float* wq    = (const float*)d_in[3];
  const float* bq    = (const float*)d_in[4];
  const float* wk    = (const float*)d_in[5];
  const float* bk    = (const float*)d_in[6];
  const float* wv    = (const float*)d_in[7];
  const float* bv    = (const float*)d_in[8];
  const float* in_w  = (const float*)d_in[9];
  const float* in_b  = (const float*)d_in[10];
  const float* out_w = (const float*)d_in[11];
  const float* out_b = (const float*)d_in[12];
  const float* fus_w = (const float*)d_in[13];
  const float* fus_b = (const float*)d_in[14];
  (void)in_sizes; (void)n_in; (void)out_size; (void)ws_size;

  float* outF  = (float*)d_out;
  float* outW0 = outF + (long)4 * 2048 * 1024;

  // ---- workspace layout (~200 MB, with region aliasing) ----
  char* base = (char*)d_ws;
  size_t off = 0;
  auto alloc = [&](size_t bytes) -> void* {
    void* p = base + off;
    off = (off + bytes + 255) & ~(size_t)255;
    return p;
  };
  const long NX = (long)8192 * 1024;
  u16* Wqb   = (u16*)alloc(1024 * 1024 * 2);   // Wqb,Wkb,Wvb contiguous (stride 1M el)
  u16* Wkb   = (u16*)alloc(1024 * 1024 * 2);
  u16* Wvb   = (u16*)alloc(1024 * 1024 * 2);
  u16* Wfb   = (u16*)alloc(1024 * 1024 * 2);
  u16* Winb  = (u16*)alloc(4 * 768 * 256 * 2);
  u16* Woutb = (u16*)alloc(4 * 256 * 256 * 2);
  float* Bias3 = (float*)alloc(3 * 1024 * 4);
  // region X: converted inputs (48 MB); after QKV proj reused for QH/KH/VHT
  char* regX = (char*)alloc((size_t)3 * NX * 2);
  u16* Xq = (u16*)regX; u16* Xk = Xq + NX; u16* Xv = Xk + NX;
  u16* QH  = (u16*)regX;                        // 4*8192*256 el = 16 MB
  u16* KH  = QH + (long)4 * 8192 * 256;         // 15360*256 el
  u16* VHT = KH + (long)15360 * 256;            // 15360*256 el  (total 32.5 MB <= 48)
  // region Y: Qp/Kp/Vp (48 MB); after in-proj reused for PP (32 MB) + AO (16 MB)
  char* regY = (char*)alloc((size_t)3 * NX * 2);
  u16* Qp = (u16*)regY; u16* Kp = Qp + NX; u16* Vp = Kp + NX;
  float* PP = (float*)regY;                     // up to 4 * 2M fp32 = 32 MB
  u16* AO   = (u16*)(regY + (size_t)32 * 1024 * 1024);  // 4 * 2M bf16 = 16 MB
  u16* PoolK = (u16*)alloc((size_t)15360 * 256 * 2);
  u16* PoolV = (u16*)alloc((size_t)15360 * 256 * 2);
  u16* SC    = (u16*)alloc((size_t)8 * 2048 * 2048 * 2);
  u16* OUTS  = (u16*)alloc((size_t)8192 * 1024 * 2);

  const long rOff[4] = {0, 8192, 12288, 14336};      // row offsets in PoolK/KH/VHT
  const long AOsz = (long)8192 * 256;                // 2M elements per scale

  // ---- converts ----
  k_cvt<<<1024, 256, 0, stream>>>(query, Xq, NX);
  k_cvt<<<1024, 256, 0, stream>>>(key_,  Xk, NX);
  k_cvt<<<1024, 256, 0, stream>>>(value, Xv, NX);
  k_cvt<<<256, 256, 0, stream>>>(wq, Wqb, 1024 * 1024);
  k_cvt<<<256, 256, 0, stream>>>(wk, Wkb, 1024 * 1024);
  k_cvt<<<256, 256, 0, stream>>>(wv, Wvb, 1024 * 1024);
  k_cvt<<<256, 256, 0, stream>>>(fus_w, Wfb, 1024 * 1024);
  k_cvt<<<192, 256, 0, stream>>>(in_w, Winb, 4 * 768 * 256);
  k_cvt<<<64, 256, 0, stream>>>(out_w, Woutb, 4 * 256 * 256);
  hipMemcpyAsync(Bias3,        bq, 4096, hipMemcpyDeviceToDevice, stream);
  hipMemcpyAsync(Bias3 + 1024, bk, 4096, hipMemcpyDeviceToDevice, stream);
  hipMemcpyAsync(Bias3 + 2048, bv, 4096, hipMemcpyDeviceToDevice, stream);

  // ---- QKV projections, batched z=3: grid (8,64,3) ----
  k_gemm<1><<<dim3(8, 64, 3), 256, 0, stream>>>(
      Xq, 1024, 0, NX, Wqb, 1024, 0, (long)1024 * 1024,
      Qp, 1024, 0, NX, 0, Bias3, 1024, 1.f, 8192, 1024, 1024, 3, 1);

  // ---- pooling (s=1 copy for scale 0 unifies layout) ----
  for (int i = 0; i < 4; i++) {
    int s = 1 << i, Ls = 2048 >> i;
    k_pool<<<4 * Ls, 256, 0, stream>>>(Kp, PoolK + rOff[i] * 256, s, Ls, i * 256);
    k_pool<<<4 * Ls, 256, 0, stream>>>(Vp, PoolV + rOff[i] * 256, s, Ls, i * 256);
  }

  // ---- in-projections, each batched over 4 scales: grid (4,64,4) ----
  {
    long4 aQ = {0, 256, 512, 768};
    long4 cQ = {0, AOsz, 2 * AOsz, 3 * AOsz};
    int4  m8 = {8192, 8192, 8192, 8192};
    long4 aP = {rOff[0] * 256, rOff[1] * 256, rOff[2] * 256, rOff[3] * 256};
    int4  mP = {8192, 4096, 2048, 1024};
    int4  ls = {2048, 1024, 512, 256};
    k_gemm_sm<0><<<dim3(4, 64, 4), 256, 0, stream>>>(
        Qp, 1024, aQ, Winb, 256, (long)768 * 256,
        QH, 256, cQ, in_b, 768, m8, 256, ls);
    k_gemm_sm<0><<<dim3(4, 64, 4), 256, 0, stream>>>(
        PoolK, 256, aP, Winb + 256 * 256, 256, (long)768 * 256,
        KH, 256, aP, in_b + 256, 768, mP, 256, ls);
    k_gemm_sm<1><<<dim3(4, 64, 4), 256, 0, stream>>>(
        PoolV, 256, aP, Winb + 2 * 256 * 256, 256, (long)768 * 256,
        VHT, 0, aP, in_b + 512, 768, mP, 256, ls);
  }

  // ---- per-scale attention ----
  const int ksArr[4] = {4, 4, 2, 2};
  for (int i = 0; i < 4; i++) {
    int Lk = 2048 >> i;
    // scores = qh . kh^T / sqrt(128): grid (Lk/128, 16, 8)
    k_gemm<1><<<dim3(Lk / 128, 16, 8), 256, 0, stream>>>(
        QH + (long)i * AOsz, 256, (long)2048 * 256, 128,
        KH + rOff[i] * 256, 256, (long)Lk * 256, 128,
        SC, Lk, (long)2 * 2048 * Lk, (long)2048 * Lk, 0,
        nullptr, 0, 0.08838834764831845f, 2048, Lk, 128, 2, 1);
    if (i == 0)      k_softmax0<<<8192, 256, 0, stream>>>(SC, outW0);
    else if (i == 1) k_softmax<1024><<<16384, 256, 0, stream>>>(SC);
    else if (i == 2) k_softmax<512><<<16384, 256, 0, stream>>>(SC);
    else             k_softmax<256><<<16384, 256, 0, stream>>>(SC);
    // PV with split-K: fp32 partials, grid (1, 16, 8*KS)
    int KS = ksArr[i], Kper = Lk / KS;
    k_gemm<0><<<dim3(1, 16, 8 * KS), 256, 0, stream>>>(
        SC, Lk, (long)2 * 2048 * Lk, (long)2048 * Lk,
        VHT + rOff[i] * 256, Lk, (long)2 * 128 * Lk, (long)128 * Lk,
        PP, 256, (long)2048 * 256, 128, AOsz,
        nullptr, 0, 1.f, 2048, 128, Kper, 2, KS);
    if (KS == 4) k_ksum<4><<<2048, 256, 0, stream>>>(PP, AO + (long)i * AOsz, AOsz);
    else         k_ksum<2><<<2048, 256, 0, stream>>>(PP, AO + (long)i * AOsz, AOsz);
  }

  // ---- out-projections batched z=4: grid (4,64,4) ----
  {
    long4 aA = {0, AOsz, 2 * AOsz, 3 * AOsz};
    long4 cO = {0, 256, 512, 768};
    int4  m8 = {8192, 8192, 8192, 8192};
    int4  ls = {1, 1, 1, 1};
    k_gemm_sm<0><<<dim3(4, 64, 4), 256, 0, stream>>>(
        AO, 256, aA, Woutb, 256, (long)256 * 256,
        OUTS, 1024, cO, out_b, 256, m8, 256, ls);
  }

  // ---- fusion GEMM: fp32 out ----
  k_gemm<0><<<dim3(8, 64, 1), 256, 0, stream>>>(
      OUTS, 1024, 0, 0, Wfb, 1024, 0, 0,
      d_out, 1024, 0, 0, 0, fus_b, 1024, 1.f, 8192, 1024, 1024, 1, 1);
}